// Round 3
// baseline (892.288 us; speedup 1.0000x reference)
//
#include <hip/hip_runtime.h>

#define HH 256
#define WW 384
#define HWSZ (HH*WW)
#define NL 3
#define A2N 49
#define NBATCH 2
#define CN 3
#define RANKN 4
#define PADW (WW + 4)   // 2-col clamp-halo each side

// Block = one output row (384 threads) for one (n, kidx); computes all 7 lidx
// views x 3 channels. Rank is the OUTER loop so the layer-product accumulator
// is only acc[7][3] (21 regs) -- the R2 spill (acc[7][12]=84 regs, 1.5 GB of
// scratch traffic) is structurally impossible here. 12 stages = (rank,layer),
// one barrier each, double-buffered vlerp rows in LDS, next stage's global
// loads prefetched before the barrier.
__global__ __launch_bounds__(WW) void multilayer_kernel(
    const float* __restrict__ low_rank,   // (N, L, R, C, H, W)
    const float* __restrict__ planes,     // (N, L)
    float* __restrict__ out)              // (N, A2, C, H, W)
{
    __shared__ float vbuf[2][CN][PADW];   // 2*3*388*4 = 9312 B

    // XCD-banded mapping: 3584 = 8 xcd * 32 y-band * 14 (n,k)
    int b   = blockIdx.x;
    int xcd = b & 7;
    int i   = b >> 3;
    int y   = (xcd << 5) + (i & 31);
    int nk  = i >> 5;                     // 0..13
    int kq  = nk % 7;
    int n   = nk / 7;

    int x = threadIdx.x;

    // ---- per-layer precompute (uniform vertical, per-(l,j) horizontal) ----
    int   y0a[NL];
    float wya[NL];
    float wxa[NL][7];
    int   ida[NL][7];                     // LDS col index = 2 + x + floor(dx)
#pragma unroll
    for (int l = 0; l < NL; l++) {
        float p  = planes[n * NL + l];
        float dy = p * (float)(3 - kq) * (255.0f / 512.0f);
        float Y  = fminf(fmaxf((float)y + dy, 0.0f), 255.0f);
        float y0c = fminf(floorf(Y), 254.0f);
        y0a[l] = (int)y0c;
        wya[l] = Y - y0c;
#pragma unroll
        for (int j = 0; j < 7; j++) {
            float dx = p * (float)(3 - j) * (383.0f / 768.0f);
            float of = floorf(dx);
            wxa[l][j] = dx - of;
            ida[l][j] = x + 2 + (int)of;
        }
    }

    float sum[7][CN];
#pragma unroll
    for (int j = 0; j < 7; j++)
#pragma unroll
        for (int c = 0; c < CN; c++) sum[j][c] = 0.0f;

    // prefetch stage 0 (r=0, l=0)
    float g0[CN], g1[CN];
    {
        const float* p0 = low_rank + (size_t)((n * NL + 0) * RANKN + 0) * CN * HWSZ
                          + y0a[0] * WW + x;
#pragma unroll
        for (int c = 0; c < CN; c++) {
            g0[c] = p0[c * HWSZ];
            g1[c] = p0[c * HWSZ + WW];
        }
    }

#pragma unroll
    for (int r = 0; r < RANKN; r++) {
        float acc[7][CN];
#pragma unroll
        for (int j = 0; j < 7; j++)
#pragma unroll
            for (int c = 0; c < CN; c++) acc[j][c] = 1.0f;

#pragma unroll
        for (int l = 0; l < NL; l++) {
            const int s   = r * NL + l;   // compile-time after unroll
            const int par = s & 1;
            float wy = wya[l];

            // vlerp + stage (halo stores clamped border value)
#pragma unroll
            for (int c = 0; c < CN; c++) {
                float v = fmaf(wy, g1[c] - g0[c], g0[c]);
                vbuf[par][c][2 + x] = v;
                if (x == 0)      { vbuf[par][c][0] = v;        vbuf[par][c][1] = v; }
                if (x == WW - 1) { vbuf[par][c][PADW - 2] = v; vbuf[par][c][PADW - 1] = v; }
            }

            // prefetch next stage's rows (independent of LDS)
            if (s + 1 < RANKN * NL) {
                const int rn = (s + 1) / NL, ln = (s + 1) % NL;
                const float* p0 = low_rank
                    + (size_t)((n * NL + ln) * RANKN + rn) * CN * HWSZ
                    + y0a[ln] * WW + x;
#pragma unroll
                for (int c = 0; c < CN; c++) {
                    g0[c] = p0[c * HWSZ];
                    g1[c] = p0[c * HWSZ + WW];
                }
            }

            __syncthreads();

            // consume: 7 views x 3 channels, pair reads -> ds_read2_b32
#pragma unroll
            for (int c = 0; c < CN; c++) {
                const float* row = &vbuf[par][c][0];
#pragma unroll
                for (int j = 0; j < 7; j++) {
                    int id = ida[l][j];
                    float a0 = row[id];
                    float a1 = row[id + 1];
                    acc[j][c] *= fmaf(wxa[l][j], a1 - a0, a0);
                }
            }
        }

#pragma unroll
        for (int j = 0; j < 7; j++)
#pragma unroll
            for (int c = 0; c < CN; c++) sum[j][c] += acc[j][c];
    }

    // epilogue: mean over rank, coalesced stores
    size_t rowoff = (size_t)y * WW + x;
#pragma unroll
    for (int j = 0; j < 7; j++) {
        int a = kq * 7 + j;
        size_t ob = ((size_t)(n * A2N + a) * CN) * HWSZ + rowoff;
#pragma unroll
        for (int c = 0; c < CN; c++)
            out[ob + (size_t)c * HWSZ] = 0.25f * sum[j][c];
    }
}

extern "C" void kernel_launch(void* const* d_in, const int* in_sizes, int n_in,
                              void* d_out, int out_size, void* d_ws, size_t ws_size,
                              hipStream_t stream) {
    const float* low_rank = (const float*)d_in[0];
    const float* planes   = (const float*)d_in[1];
    float* out = (float*)d_out;

    int blocks = 8 * 32 * (NBATCH * 7);   // 3584
    multilayer_kernel<<<blocks, WW, 0, stream>>>(low_rank, planes, out);
}

// Round 4
// 682.203 us; speedup vs baseline: 1.3079x; 1.3079x over previous
//
#include <hip/hip_runtime.h>

#define HH 256
#define WW 384
#define HWSZ (HH*WW)
#define NL 3
#define A2N 49
#define NBATCH 2
#define CN 3
#define RANKN 4
#define PADW (WW + 4)   // 2-col clamp-halo each side

// All sampling parameters (wx, ox, wy, y0) are block-uniform -> force into
// SGPRs so per-thread VGPR state is just acc[7][3]+sum[7][3]+pipeline (~80).
// R2/R3 died on scratch spill (WRITE_SIZE 1.5 GB, VGPR pinned at the 128 cap)
// because these uniforms lived in VGPRs (48 regs of them).
__device__ __forceinline__ float uniform_f(float v) {
    return __int_as_float(__builtin_amdgcn_readfirstlane(__float_as_int(v)));
}
__device__ __forceinline__ int uniform_i(int v) {
    return __builtin_amdgcn_readfirstlane(v);
}

__global__ __launch_bounds__(WW) void multilayer_kernel(
    const float* __restrict__ low_rank,   // (N, L, R, C, H, W)
    const float* __restrict__ planes,     // (N, L)
    float* __restrict__ out)              // (N, A2, C, H, W)
{
    __shared__ float vbuf[2][CN][PADW];   // 9312 B, double-buffered vlerp rows

    // XCD-banded mapping: 3584 = 8 xcd * 32 y-band * 14 (n,k)
    int b   = blockIdx.x;
    int xcd = b & 7;
    int i   = b >> 3;
    int y   = (xcd << 5) + (i & 31);
    int nk  = i >> 5;                     // 0..13
    int kq  = nk % 7;
    int n   = nk / 7;

    int x = threadIdx.x;

    // ---- block-uniform sampling parameters -> SGPRs ----
    int   y0a[NL];                        // uniform
    float wya[NL];                        // uniform
    float wxs[NL][7];                     // uniform
    int   oxs[NL][7];                     // uniform, in {-2..1}
#pragma unroll
    for (int l = 0; l < NL; l++) {
        float p  = planes[n * NL + l];
        float dy = p * (float)(3 - kq) * (255.0f / 512.0f);
        float Y  = fminf(fmaxf((float)y + dy, 0.0f), 255.0f);
        float y0c = fminf(floorf(Y), 254.0f);
        y0a[l] = uniform_i((int)y0c);
        wya[l] = uniform_f(Y - y0c);
#pragma unroll
        for (int j = 0; j < 7; j++) {
            float dx = p * (float)(3 - j) * (383.0f / 768.0f);
            float of = floorf(dx);
            wxs[l][j] = uniform_f(dx - of);
            oxs[l][j] = uniform_i((int)of);
        }
    }

    float sum[7][CN];
#pragma unroll
    for (int j = 0; j < 7; j++)
#pragma unroll
        for (int c = 0; c < CN; c++) sum[j][c] = 0.0f;

    // prefetch stage 0 (r=0, l=0)
    float g0[CN], g1[CN];
    {
        const float* p0 = low_rank + (size_t)((n * NL + 0) * RANKN + 0) * CN * HWSZ
                          + y0a[0] * WW + x;
#pragma unroll
        for (int c = 0; c < CN; c++) {
            g0[c] = p0[c * HWSZ];
            g1[c] = p0[c * HWSZ + WW];
        }
    }

#pragma unroll
    for (int r = 0; r < RANKN; r++) {
        float acc[7][CN];
#pragma unroll
        for (int j = 0; j < 7; j++)
#pragma unroll
            for (int c = 0; c < CN; c++) acc[j][c] = 1.0f;

#pragma unroll
        for (int l = 0; l < NL; l++) {
            const int s   = r * NL + l;   // compile-time after unroll
            const int par = s & 1;
            float wy = wya[l];

            // vlerp + stage (halo stores replicate the border value)
#pragma unroll
            for (int c = 0; c < CN; c++) {
                float v = fmaf(wy, g1[c] - g0[c], g0[c]);
                vbuf[par][c][2 + x] = v;
                if (x == 0)      { vbuf[par][c][0] = v;        vbuf[par][c][1] = v; }
                if (x == WW - 1) { vbuf[par][c][PADW - 2] = v; vbuf[par][c][PADW - 1] = v; }
            }

            // prefetch next stage's rows (independent of LDS)
            if (s + 1 < RANKN * NL) {
                const int rn = (s + 1) / NL, ln = (s + 1) % NL;
                const float* p0 = low_rank
                    + (size_t)((n * NL + ln) * RANKN + rn) * CN * HWSZ
                    + y0a[ln] * WW + x;
#pragma unroll
                for (int c = 0; c < CN; c++) {
                    g0[c] = p0[c * HWSZ];
                    g1[c] = p0[c * HWSZ + WW];
                }
            }

            __syncthreads();

            // consume: 7 views x 3 channels; addr = vgpr(x) + sgpr(ox)
#pragma unroll
            for (int c = 0; c < CN; c++) {
                const float* rowp = &vbuf[par][c][2 + x];
#pragma unroll
                for (int j = 0; j < 7; j++) {
                    int o = oxs[l][j];
                    float a0 = rowp[o];
                    float a1 = rowp[o + 1];
                    acc[j][c] *= fmaf(wxs[l][j], a1 - a0, a0);
                }
            }
        }

#pragma unroll
        for (int j = 0; j < 7; j++)
#pragma unroll
            for (int c = 0; c < CN; c++) sum[j][c] += acc[j][c];
    }

    // epilogue: mean over rank, coalesced stores
    size_t rowoff = (size_t)y * WW + x;
#pragma unroll
    for (int j = 0; j < 7; j++) {
        int a = kq * 7 + j;
        size_t ob = ((size_t)(n * A2N + a) * CN) * HWSZ + rowoff;
#pragma unroll
        for (int c = 0; c < CN; c++)
            out[ob + (size_t)c * HWSZ] = 0.25f * sum[j][c];
    }
}

extern "C" void kernel_launch(void* const* d_in, const int* in_sizes, int n_in,
                              void* d_out, int out_size, void* d_ws, size_t ws_size,
                              hipStream_t stream) {
    const float* low_rank = (const float*)d_in[0];
    const float* planes   = (const float*)d_in[1];
    float* out = (float*)d_out;

    int blocks = 8 * 32 * (NBATCH * 7);   // 3584
    multilayer_kernel<<<blocks, WW, 0, stream>>>(low_rank, planes, out);
}